// Round 1
// baseline (1912.221 us; speedup 1.0000x reference)
//
#include <hip/hip_runtime.h>
#include <hip/hip_bf16.h>

#define HIDDEN   512
#define TSTEPS   256
#define HORIZON  24
#define BTOT     1024
#define BBLK     16
#define NWG      (BTOT / BBLK)      // 64 workgroups, one per CU
#define NTHR     512                // 8 waves
#define NTPW     4                  // 16-col N-tiles per wave (64 cols/wave)
#define KK       16                 // K iterations (512 / 32)

typedef __attribute__((ext_vector_type(8))) __bf16         bf16x8;
typedef __attribute__((ext_vector_type(4))) float          f32x4;
typedef __attribute__((ext_vector_type(8))) unsigned short ushort8;

__device__ __forceinline__ unsigned short f2bf(float f) {
    unsigned int u = __float_as_uint(f);
    u += 0x7FFFu + ((u >> 16) & 1u);   // round-to-nearest-even
    return (unsigned short)(u >> 16);
}
__device__ __forceinline__ float bf2f(unsigned short s) {
    return __uint_as_float(((unsigned int)s) << 16);
}

// Pack Wh (f32 [512][512], row j = output column, inner k) into bf16 MFMA
// B-fragment order. Fragment index (kk, ntg, lane) holds 8 bf16:
//   n = ntg*16 + (lane&15), k = kk*32 + (lane>>4)*8 + j
// This k-mapping matches the A-frag LDS read in the main kernel, so any
// bijective per-slot k permutation in HW cancels in the dot product.
__global__ void pack_wh(const float* __restrict__ Wh, ushort8* __restrict__ Wpk) {
    int tid  = blockIdx.x * blockDim.x + threadIdx.x;   // 0..32767
    int lane = tid & 63;
    int ntg  = (tid >> 6) & 31;
    int kk   = tid >> 11;
    int col  = ntg * 16 + (lane & 15);
    int k0   = kk * 32 + ((lane >> 4) & 3) * 8;
    const float* src = Wh + col * HIDDEN + k0;
    ushort8 v;
#pragma unroll
    for (int j = 0; j < 8; ++j) v[j] = f2bf(src[j]);
    Wpk[tid] = v;
}

__global__ __launch_bounds__(NTHR) void rnn_main(
    const float* __restrict__ x,      // [1024][256]
    const float* __restrict__ Wx_w,   // [512]
    const float* __restrict__ Wx_b,   // [512]
    const float* __restrict__ Wh_b,   // [512]
    const float* __restrict__ fc_w,   // [24][512]
    const float* __restrict__ fc_b,   // [24]
    const bf16x8* __restrict__ Wpk,   // packed bf16 fragments (512 KB)
    float* __restrict__ out)          // [1024][24]
{
    // h double-buffer, bf16, XOR-swizzled rows (byte ^= (row&7)<<4) to kill
    // the 16-way bank conflict of stride-1024B ds_read_b128.
    __shared__ __align__(16) unsigned short hbuf[2][BBLK * HIDDEN];   // 2 x 16 KB
    __shared__ float xs[TSTEPS][BBLK];                                 // 16 KB

    const int tid  = threadIdx.x;
    const int lane = tid & 63;
    const int wave = tid >> 6;
    const int bb   = blockIdx.x * BBLK;
    const int arow = lane & 15;
    const int rowg = lane >> 4;

    // stage x transposed: xs[t][r]  (coalesced global reads along t)
    for (int i = tid; i < BBLK * TSTEPS; i += NTHR) {
        int r = i >> 8;
        int t = i & 255;
        xs[t][r] = x[(bb + r) * TSTEPS + t];
    }
    // h0 = 0
    for (int i = tid; i < BBLK * HIDDEN; i += NTHR) hbuf[0][i] = 0;

    // per-lane step-invariant constants: Wx_w and fused bias for my 4 n-tiles
    float wxw_c[NTPW], bias_c[NTPW];
#pragma unroll
    for (int nt = 0; nt < NTPW; ++nt) {
        int col = wave * 64 + nt * 16 + arow;
        wxw_c[nt]  = Wx_w[col];
        bias_c[nt] = Wx_b[col] + Wh_b[col];
    }

    // step-invariant weight fragment base for this (wave, lane)
    const bf16x8* wbase = Wpk + wave * 4 * 64 + lane;

    __syncthreads();

    for (int t = 0; t < TSTEPS; ++t) {
        const char* hr = (const char*)hbuf[t & 1];
        char*       hw = (char*)hbuf[(t + 1) & 1];

        float xv[4];
#pragma unroll
        for (int r = 0; r < 4; ++r) xv[r] = xs[t][rowg * 4 + r];

        // acc init = x_t * Wx_w + (Wx_b + Wh_b), per verified C/D layout:
        // D[row=(lane>>4)*4+r][col=lane&15]
        f32x4 acc[NTPW];
#pragma unroll
        for (int nt = 0; nt < NTPW; ++nt) {
#pragma unroll
            for (int r = 0; r < 4; ++r) acc[nt][r] = xv[r] * wxw_c[nt] + bias_c[nt];
        }

        // K-loop: A (h) from LDS, B (Wh) streamed from L2, double-buffered
        bf16x8 c0 = wbase[0];
        bf16x8 c1 = wbase[64];
        bf16x8 c2 = wbase[128];
        bf16x8 c3 = wbase[192];
#pragma unroll
        for (int kk = 0; kk < KK; ++kk) {
            bf16x8 n0, n1, n2, n3;
            if (kk < KK - 1) {
                const bf16x8* wn = wbase + (kk + 1) * 2048;
                n0 = wn[0]; n1 = wn[64]; n2 = wn[128]; n3 = wn[192];
            }
            int abyte = (arow * 1024 + kk * 64 + rowg * 16) ^ ((arow & 7) << 4);
            bf16x8 af = *(const bf16x8*)(hr + abyte);
            acc[0] = __builtin_amdgcn_mfma_f32_16x16x32_bf16(af, c0, acc[0], 0, 0, 0);
            acc[1] = __builtin_amdgcn_mfma_f32_16x16x32_bf16(af, c1, acc[1], 0, 0, 0);
            acc[2] = __builtin_amdgcn_mfma_f32_16x16x32_bf16(af, c2, acc[2], 0, 0, 0);
            acc[3] = __builtin_amdgcn_mfma_f32_16x16x32_bf16(af, c3, acc[3], 0, 0, 0);
            if (kk < KK - 1) { c0 = n0; c1 = n1; c2 = n2; c3 = n3; }
        }

        // tanh + bf16 + write to next h buffer (same swizzle)
#pragma unroll
        for (int nt = 0; nt < NTPW; ++nt) {
            int colb = (wave * 64 + nt * 16 + arow) * 2;
#pragma unroll
            for (int r = 0; r < 4; ++r) {
                int row = rowg * 4 + r;
                float v = acc[nt][r];
                // tanh(v) = 1 - 2/(exp(2v)+1); saturates cleanly at +/-1, no NaN
                float e  = __expf(2.0f * v);
                float th = 1.0f - 2.0f / (e + 1.0f);
                int wbyte = (row * 1024 + colb) ^ ((row & 7) << 4);
                *(unsigned short*)(hw + wbyte) = f2bf(th);
            }
        }
        __syncthreads();
    }

    // TSTEPS even -> final h lives in hbuf[0]. Small fc head: 16x24 outputs.
    const char* hf = (const char*)hbuf[0];
    if (tid < BBLK * HORIZON) {
        int row = tid / HORIZON;
        int ho  = tid - row * HORIZON;
        float acc = fc_b[ho];
        const float* fw = fc_w + ho * HIDDEN;
#pragma unroll 4
        for (int k = 0; k < HIDDEN; k += 8) {
            int abyte = (row * 1024 + k * 2) ^ ((row & 7) << 4);
            ushort8 hv = *(const ushort8*)(hf + abyte);
#pragma unroll
            for (int j = 0; j < 8; ++j) acc += bf2f(hv[j]) * fw[k + j];
        }
        out[(bb + row) * HORIZON + ho] = acc;
    }
}

extern "C" void kernel_launch(void* const* d_in, const int* in_sizes, int n_in,
                              void* d_out, int out_size, void* d_ws, size_t ws_size,
                              hipStream_t stream) {
    const float* x    = (const float*)d_in[0];
    const float* Wx_w = (const float*)d_in[1];
    const float* Wx_b = (const float*)d_in[2];
    const float* Wh_w = (const float*)d_in[3];
    const float* Wh_b = (const float*)d_in[4];
    const float* fc_w = (const float*)d_in[5];
    const float* fc_b = (const float*)d_in[6];
    float* out = (float*)d_out;

    ushort8* Wpk = (ushort8*)d_ws;   // 512 KB of workspace for packed weights

    hipLaunchKernelGGL(pack_wh, dim3(128), dim3(256), 0, stream, Wh_w, Wpk);
    hipLaunchKernelGGL(rnn_main, dim3(NWG), dim3(NTHR), 0, stream,
                       x, Wx_w, Wx_b, Wh_b, fc_w, fc_b,
                       (const bf16x8*)Wpk, out);
}

// Round 3
// 1536.709 us; speedup vs baseline: 1.2444x; 1.2444x over previous
//
#include <hip/hip_runtime.h>
#include <hip/hip_bf16.h>

#define HIDDEN   512
#define TSTEPS   256
#define HORIZON  24
#define BTOT     1024
#define BBLK     16
#define NWG      (BTOT / BBLK)      // 64 workgroups
#define NTHR     512                // 8 waves
#define KK       16                 // K slices (512 / 32)

typedef __attribute__((ext_vector_type(8))) __bf16         bf16x8;
typedef __attribute__((ext_vector_type(4))) float          f32x4;
typedef __attribute__((ext_vector_type(8))) unsigned short ushort8;
typedef __attribute__((ext_vector_type(4))) unsigned short us4;
typedef __attribute__((ext_vector_type(4))) unsigned int   uint4v;

__device__ __forceinline__ unsigned short f2bf(float f) {
    unsigned int u = __float_as_uint(f);
    u += 0x7FFFu + ((u >> 16) & 1u);   // RNE
    return (unsigned short)(u >> 16);
}
__device__ __forceinline__ float bf2f(unsigned short s) {
    return __uint_as_float(((unsigned int)s) << 16);
}

// Pack Wh (f32 [512][512], row j = out-col, inner k) into bf16 A-fragment
// order, m-tile-major: Wpk[(ntg*16 + kk)*64 + lane] holds 8 bf16 of
//   A[m = ntg*16 + (lane&15)][k = kk*32 + ((lane>>4)&3)*8 + j]
__global__ void pack_wh(const float* __restrict__ Wh, ushort8* __restrict__ Wpk) {
    int tid  = blockIdx.x * blockDim.x + threadIdx.x;   // 0..32767
    int lane = tid & 63;
    int kk   = (tid >> 6) & 15;
    int ntg  = tid >> 10;                                // global m-tile 0..31
    int col  = ntg * 16 + (lane & 15);                   // out-col
    int k0   = kk * 32 + ((lane >> 4) & 3) * 8;
    const float* src = Wh + col * HIDDEN + k0;
    ushort8 v;
#pragma unroll
    for (int j = 0; j < 8; ++j) v[j] = f2bf(src[j]);
    Wpk[(ntg * 16 + kk) * 64 + lane] = v;
}

__global__ __launch_bounds__(NTHR) void rnn_main(
    const float* __restrict__ x,      // [1024][256]
    const float* __restrict__ Wx_w,   // [512]
    const float* __restrict__ Wx_b,   // [512]
    const float* __restrict__ Wh_b,   // [512]
    const float* __restrict__ fc_w,   // [24][512]
    const float* __restrict__ fc_b,   // [24]
    const bf16x8* __restrict__ Wpk,   // packed bf16 A-fragments (512 KB)
    float* __restrict__ out)          // [1024][24]
{
    // h in B-fragment-major layout: hfrag[buf][(kk*64 + lane)*8 ushorts]
    // lane l's B-frag for slice kk = h[row=l&15][k = kk*32 + (l>>4)*8 .. +7]
    __shared__ __align__(16) unsigned short hfrag[2][KK * 64 * 8];  // 2 x 16 KB
    __shared__ float xs[TSTEPS][BBLK];                               // 16 KB

    const int tid  = threadIdx.x;
    const int lane = tid & 63;
    const int wave = tid >> 6;
    const int bb   = blockIdx.x * BBLK;
    const int arow = lane & 15;      // A/B n-index; C/D col = batch row
    const int rowg = lane >> 4;

    // stage x transposed: xs[t][r]
    for (int i = tid; i < BBLK * TSTEPS; i += NTHR) {
        int t = i & 255, r = i >> 8;
        xs[t][r] = x[(bb + r) * TSTEPS + t];
    }
    // h0 = 0
    {
        uint4v z = {0u, 0u, 0u, 0u};
        uint4v* p = (uint4v*)hfrag[0];
        p[tid] = z; p[tid + NTHR] = z;
    }

    // ---- static weights: m-tiles 0,1 in registers (128 VGPRs) ----
    const bf16x8* wp0 = Wpk + ((wave * 4 + 0) * 16) * 64 + lane;
    const bf16x8* wp1 = Wpk + ((wave * 4 + 1) * 16) * 64 + lane;
    bf16x8 W0[KK], W1[KK];
#pragma unroll
    for (int kk = 0; kk < KK; ++kk) { W0[kk] = wp0[kk * 64]; W1[kk] = wp1[kk * 64]; }

    // ---- streamed weights: m-tiles 2,3 via 4-deep circular reg buffer ----
    const bf16x8* wp2 = Wpk + ((wave * 4 + 2) * 16) * 64 + lane;
    const bf16x8* wp3 = Wpk + ((wave * 4 + 3) * 16) * 64 + lane;
    bf16x8 sb2[4], sb3[4];
#pragma unroll
    for (int i = 0; i < 4; ++i) { sb2[i] = wp2[i * 64]; sb3[i] = wp3[i * 64]; }

    // per-lane step-invariant init constants: out-col = wave*64+mt*16+rowg*4+r
    f32x4 wxw_c[4], bias_c[4];
#pragma unroll
    for (int mt = 0; mt < 4; ++mt) {
#pragma unroll
        for (int r = 0; r < 4; ++r) {
            int oc = wave * 64 + mt * 16 + rowg * 4 + r;
            wxw_c[mt][r]  = Wx_w[oc];
            bias_c[mt][r] = Wx_b[oc] + Wh_b[oc];
        }
    }

    __syncthreads();

#pragma unroll 2
    for (int t = 0; t < TSTEPS; ++t) {
        const unsigned short* hr = hfrag[t & 1];
        unsigned short*       hw = hfrag[(t + 1) & 1];

        const float xv = xs[t][arow];   // batch row = arow (broadcast)

        f32x4 acc[4];
#pragma unroll
        for (int mt = 0; mt < 4; ++mt)
#pragma unroll
            for (int r = 0; r < 4; ++r) acc[mt][r] = xv * wxw_c[mt][r] + bias_c[mt][r];

#pragma unroll
        for (int kk = 0; kk < KK; ++kk) {
            bf16x8 bf = *(const bf16x8*)(hr + (kk * 64 + lane) * 8);
            acc[0] = __builtin_amdgcn_mfma_f32_16x16x32_bf16(W0[kk], bf, acc[0], 0, 0, 0);
            acc[1] = __builtin_amdgcn_mfma_f32_16x16x32_bf16(W1[kk], bf, acc[1], 0, 0, 0);
            acc[2] = __builtin_amdgcn_mfma_f32_16x16x32_bf16(sb2[kk & 3], bf, acc[2], 0, 0, 0);
            acc[3] = __builtin_amdgcn_mfma_f32_16x16x32_bf16(sb3[kk & 3], bf, acc[3], 0, 0, 0);
            // refill slot (kk&3) with slice (kk+4)&15 — stream is step-invariant,
            // wraps seamlessly into the next step's kk=0..3
            sb2[kk & 3] = wp2[((kk + 4) & 15) * 64];
            sb3[kk & 3] = wp3[((kk + 4) & 15) * 64];
        }

        // epilogue: tanh, pack 4 consecutive out-cols -> one b64 frag-major write
#pragma unroll
        for (int mt = 0; mt < 4; ++mt) {
            us4 pk;
#pragma unroll
            for (int r = 0; r < 4; ++r) {
                float v  = acc[mt][r];
                float e  = __expf(2.0f * v);
                pk[r] = f2bf(1.0f - 2.0f / (e + 1.0f));
            }
            // out-col base = wave*64 + mt*16 + rowg*4 ; batch row = arow
            int kkp   = wave * 2 + (mt >> 1);
            int chunk = (mt * 2 + (rowg >> 1)) & 3;
            int j0    = (rowg & 1) * 4;
            *(us4*)(hw + (kkp * 64 + chunk * 16 + arow) * 8 + j0) = pk;
        }
        __syncthreads();
    }

    // final h is in hfrag[0] (TSTEPS even). fc head: 16 x 24 outputs.
    if (tid < BBLK * HORIZON) {
        int row = tid / HORIZON;
        int ho  = tid - row * HORIZON;
        float acc = fc_b[ho];
        const float* fw = fc_w + ho * HIDDEN;
        const unsigned short* hf = hfrag[0];
#pragma unroll 4
        for (int kk = 0; kk < KK; ++kk) {
#pragma unroll
            for (int c = 0; c < 4; ++c) {
                ushort8 hv = *(const ushort8*)(hf + (kk * 64 + c * 16 + row) * 8);
#pragma unroll
                for (int j = 0; j < 8; ++j)
                    acc += bf2f(hv[j]) * fw[kk * 32 + c * 8 + j];
            }
        }
        out[(bb + row) * HORIZON + ho] = acc;
    }
}

extern "C" void kernel_launch(void* const* d_in, const int* in_sizes, int n_in,
                              void* d_out, int out_size, void* d_ws, size_t ws_size,
                              hipStream_t stream) {
    const float* x    = (const float*)d_in[0];
    const float* Wx_w = (const float*)d_in[1];
    const float* Wx_b = (const float*)d_in[2];
    const float* Wh_w = (const float*)d_in[3];
    const float* Wh_b = (const float*)d_in[4];
    const float* fc_w = (const float*)d_in[5];
    const float* fc_b = (const float*)d_in[6];
    float* out = (float*)d_out;

    ushort8* Wpk = (ushort8*)d_ws;   // 512 KB packed weights

    hipLaunchKernelGGL(pack_wh, dim3(128), dim3(256), 0, stream, Wh_w, Wpk);
    hipLaunchKernelGGL(rnn_main, dim3(NWG), dim3(NTHR), 0, stream,
                       x, Wx_w, Wx_b, Wh_b, fc_w, fc_b,
                       (const bf16x8*)Wpk, out);
}